// Round 11
// baseline (7358.619 us; speedup 1.0000x reference)
//
#include <hip/hip_runtime.h>

typedef _Float16 half8 __attribute__((ext_vector_type(8)));
typedef _Float16 half4 __attribute__((ext_vector_type(4)));
typedef float floatx4 __attribute__((ext_vector_type(4)));
typedef unsigned int uintx4 __attribute__((ext_vector_type(4)));

#define CCH 256
#define LSEQ 8192
#define LTILE 64                  // output rows per block
#define AROWS 68                  // staged h rows: l0-2 .. l0+65
#define NT 128                    // tiles per batch = 8192/64
#define ROWB 512
#define LDSB (AROWS * ROWB)       // 34816 -> 4 blocks/CU (max waves)

__device__ __forceinline__ int swz(int row, int byte) {
  return row * ROWB + (byte ^ ((row & 7) << 4));
}
__device__ __forceinline__ floatx4 zero4() {
  floatx4 v; v[0] = 0.f; v[1] = 0.f; v[2] = 0.f; v[3] = 0.f; return v;
}

// R11 = R10 (dense weights [tap][kc][co][32ci], shared h/r1 LDS buffer) with
// LTILE 128->64: LDS 34.8KB -> 4 blocks/CU for max barrier-phase overlap.
// Dense weights made small tiles cheap (weight re-stream is L2-resident).
// MODE 0: dst = src + 0.15*bn2(conv2(relu(bn1(conv1(src)))))
// MODE 1: dst = relu(conv(src)*sc + sh)
template <int MODE>
__global__ __launch_bounds__(512, 1) void res3(
    const _Float16* __restrict__ src, _Float16* __restrict__ dst,
    const _Float16* __restrict__ wA, const _Float16* __restrict__ wB,
    const float* __restrict__ sc1v, const float* __restrict__ sh1v,
    const float* __restrict__ sc2v, const float* __restrict__ sh2v) {
  __shared__ __align__(16) char smem[LDSB];
  const int t = threadIdx.x;
  const int bx = blockIdx.x;
  const int b = bx >> 7;
  const int tile = bx & (NT - 1);
  const int l0 = tile * LTILE;

  // ---- stage A: 68 rows (row <-> l = l0-2+row), f16, swizzled, zero-padded
  for (int c = t; c < AROWS * 32; c += 512) {
    const int row = c >> 5, col = c & 31;
    const int l = l0 + row - 2;
    uintx4 v = {0u, 0u, 0u, 0u};
    if (l >= 0 && l < LSEQ)
      v = *(const uintx4*)(src + (((size_t)b * LSEQ + l) << 8) + col * 8);
    *(uintx4*)(smem + swz(row, col * 16)) = v;
  }
  __syncthreads();

  const int w = t >> 6, ln = t & 63;
  const int cg = w >> 1, lgrp = w & 1;  // co-group 0..3, l-half 0..1
  const int lrow = ln & 15, kgrp = ln >> 4;

  if constexpr (MODE == 0) {
    // ---- conv1 -> r1 rows r (l = l0-1+r), r 0..65 used.
    // lgrp0: j-tiles 0..2 (r 0..47); lgrp1: tiles 3..4 (r 48..79, masked >=66)
    const int jtb = lgrp ? 3 : 0;
    const int njt = lgrp ? 2 : 3;
    floatx4 acc[4][3];
#pragma unroll
    for (int i = 0; i < 4; ++i)
#pragma unroll
      for (int j = 0; j < 3; ++j) acc[i][j] = zero4();
    for (int tap = 0; tap < 3; ++tap) {
      for (int kc = 0; kc < 8; ++kc) {
        // dense: wA[((tap*8+kc)*256 + co)*32 + kgrp*8], co = cg*64+i*16+lrow
        const _Float16* wp = wA + ((size_t)((tap * 8 + kc) * CCH + cg * 64 + lrow)) * 32 + kgrp * 8;
        half8 a0 = *(const half8*)(wp);
        half8 a1 = *(const half8*)(wp + 16 * 32);
        half8 a2 = *(const half8*)(wp + 32 * 32);
        half8 a3 = *(const half8*)(wp + 48 * 32);
        const int byt = kc * 64 + kgrp * 16;
#pragma unroll
        for (int jj = 0; jj < 3; ++jj) {
          if (jj < njt) {
            int arow = (jtb + jj) * 16 + lrow + tap;  // A row = r + tap
            if (arow > AROWS - 1) arow = AROWS - 1;   // masked outputs only
            half8 bf = *(const half8*)(smem + swz(arow, byt));
            acc[0][jj] = __builtin_amdgcn_mfma_f32_16x16x32_f16(a0, bf, acc[0][jj], 0, 0, 0);
            acc[1][jj] = __builtin_amdgcn_mfma_f32_16x16x32_f16(a1, bf, acc[1][jj], 0, 0, 0);
            acc[2][jj] = __builtin_amdgcn_mfma_f32_16x16x32_f16(a2, bf, acc[2][jj], 0, 0, 0);
            acc[3][jj] = __builtin_amdgcn_mfma_f32_16x16x32_f16(a3, bf, acc[3][jj], 0, 0, 0);
          }
        }
      }
    }
    __syncthreads();  // all conv1 A-reads done before r1 overwrites the buffer
    // epilogue 1: bn1+relu -> r1 into SAME buffer at row r; zero outside seq
#pragma unroll
    for (int i = 0; i < 4; ++i) {
      const int co = cg * 64 + i * 16 + kgrp * 4;
      floatx4 s = *(const floatx4*)(sc1v + co);
      floatx4 sh = *(const floatx4*)(sh1v + co);
#pragma unroll
      for (int jj = 0; jj < 3; ++jj) {
        if (jj < njt) {
          const int r = (jtb + jj) * 16 + lrow;
          if (r < LTILE + 2) {
            const int l = l0 - 1 + r;
            const bool valid = (l >= 0) && (l < LSEQ);
            unsigned long long pk = 0;
#pragma unroll
            for (int q = 0; q < 4; ++q) {
              float y = acc[i][jj][q] * s[q] + sh[q];
              y = valid ? fmaxf(y, 0.f) : 0.f;
              unsigned short u = __builtin_bit_cast(unsigned short, (_Float16)y);
              pk |= (unsigned long long)u << (16 * q);
            }
            *(unsigned long long*)(smem + swz(r, co * 2)) = pk;
          }
        }
      }
    }
    __syncthreads();
    // ---- conv2: out row v (l = l0+v), reads r1 rows v..v+2; 2 j-tiles per lgrp
    floatx4 acc2[4][2];
#pragma unroll
    for (int i = 0; i < 4; ++i)
#pragma unroll
      for (int j = 0; j < 2; ++j) acc2[i][j] = zero4();
    for (int tap = 0; tap < 3; ++tap) {
      for (int kc = 0; kc < 8; ++kc) {
        const _Float16* wp = wB + ((size_t)((tap * 8 + kc) * CCH + cg * 64 + lrow)) * 32 + kgrp * 8;
        half8 a0 = *(const half8*)(wp);
        half8 a1 = *(const half8*)(wp + 16 * 32);
        half8 a2 = *(const half8*)(wp + 32 * 32);
        half8 a3 = *(const half8*)(wp + 48 * 32);
        const int byt = kc * 64 + kgrp * 16;
#pragma unroll
        for (int j = 0; j < 2; ++j) {
          const int brow = (lgrp * 2 + j) * 16 + lrow + tap;  // 0..65
          half8 bf = *(const half8*)(smem + swz(brow, byt));
          acc2[0][j] = __builtin_amdgcn_mfma_f32_16x16x32_f16(a0, bf, acc2[0][j], 0, 0, 0);
          acc2[1][j] = __builtin_amdgcn_mfma_f32_16x16x32_f16(a1, bf, acc2[1][j], 0, 0, 0);
          acc2[2][j] = __builtin_amdgcn_mfma_f32_16x16x32_f16(a2, bf, acc2[2][j], 0, 0, 0);
          acc2[3][j] = __builtin_amdgcn_mfma_f32_16x16x32_f16(a3, bf, acc2[3][j], 0, 0, 0);
        }
      }
    }
    // epilogue 2: y = h + 0.15*bn2; h re-read from global src (L2/LLC-resident)
#pragma unroll
    for (int i = 0; i < 4; ++i) {
      const int co = cg * 64 + i * 16 + kgrp * 4;
      floatx4 s = *(const floatx4*)(sc2v + co);
      floatx4 sh = *(const floatx4*)(sh2v + co);
#pragma unroll
      for (int j = 0; j < 2; ++j) {
        const int v = (lgrp * 2 + j) * 16 + lrow;
        const int l = l0 + v;
        const size_t off = (((size_t)b * LSEQ + l) << 8) + co;
        half4 h = *(const half4*)(src + off);
        half4 o;
#pragma unroll
        for (int q = 0; q < 4; ++q)
          o[q] = (_Float16)((float)h[q] + 0.15f * (acc2[i][j][q] * s[q] + sh[q]));
        *(half4*)(dst + off) = o;
      }
    }
  } else {
    // MODE 1: out = relu(conv(A)*sc + sh); out row v reads A rows v+1..v+3
    floatx4 acc[4][2];
#pragma unroll
    for (int i = 0; i < 4; ++i)
#pragma unroll
      for (int j = 0; j < 2; ++j) acc[i][j] = zero4();
    for (int tap = 0; tap < 3; ++tap) {
      for (int kc = 0; kc < 8; ++kc) {
        const _Float16* wp = wA + ((size_t)((tap * 8 + kc) * CCH + cg * 64 + lrow)) * 32 + kgrp * 8;
        half8 a0 = *(const half8*)(wp);
        half8 a1 = *(const half8*)(wp + 16 * 32);
        half8 a2 = *(const half8*)(wp + 32 * 32);
        half8 a3 = *(const half8*)(wp + 48 * 32);
        const int byt = kc * 64 + kgrp * 16;
#pragma unroll
        for (int j = 0; j < 2; ++j) {
          const int arow = (lgrp * 2 + j) * 16 + lrow + 1 + tap;  // 1..66
          half8 bf = *(const half8*)(smem + swz(arow, byt));
          acc[0][j] = __builtin_amdgcn_mfma_f32_16x16x32_f16(a0, bf, acc[0][j], 0, 0, 0);
          acc[1][j] = __builtin_amdgcn_mfma_f32_16x16x32_f16(a1, bf, acc[1][j], 0, 0, 0);
          acc[2][j] = __builtin_amdgcn_mfma_f32_16x16x32_f16(a2, bf, acc[2][j], 0, 0, 0);
          acc[3][j] = __builtin_amdgcn_mfma_f32_16x16x32_f16(a3, bf, acc[3][j], 0, 0, 0);
        }
      }
    }
#pragma unroll
    for (int i = 0; i < 4; ++i) {
      const int co = cg * 64 + i * 16 + kgrp * 4;
      floatx4 s = *(const floatx4*)(sc1v + co);
      floatx4 sh = *(const floatx4*)(sh1v + co);
#pragma unroll
      for (int j = 0; j < 2; ++j) {
        const int v = (lgrp * 2 + j) * 16 + lrow;
        const int l = l0 + v;
        half4 o;
#pragma unroll
        for (int q = 0; q < 4; ++q)
          o[q] = (_Float16)fmaxf(acc[i][j][q] * s[q] + sh[q], 0.f);
        *(half4*)(dst + (((size_t)b * LSEQ + l) << 8) + co) = o;
      }
    }
  }
}

// x[16][1][8192] -> h0[b][l][co] (f16) = relu(conv1d_{1->256}(x) + b_in)
__global__ void conv_in_kernel(const float* __restrict__ x, const float* __restrict__ w_in,
                               const float* __restrict__ b_in, _Float16* __restrict__ hout) {
  size_t idx = (size_t)blockIdx.x * blockDim.x + threadIdx.x;
  int co = (int)(idx & 255);
  size_t pos = idx >> 8;
  int l = (int)(pos & (LSEQ - 1));
  int b = (int)(pos >> 13);
  float acc = b_in[co];
#pragma unroll
  for (int k = 0; k < 3; ++k) {
    int lg = l + k - 1;
    if (lg >= 0 && lg < LSEQ) acc += w_in[co * 3 + k] * x[(size_t)b * LSEQ + lg];
  }
  hout[idx] = (_Float16)fmaxf(acc, 0.f);
}

// final conv 256->4 + bias + relu + pixel-shuffle: out[b][l*4+co]
__global__ __launch_bounds__(256) void conv_u2_kernel(
    const _Float16* __restrict__ hin, const float* __restrict__ w2T4 /*[tap][ci][4]*/,
    const float* __restrict__ b_u2, float* __restrict__ out) {
  const size_t idx = (size_t)blockIdx.x * 256 + threadIdx.x;  // = b*8192 + l
  const int l = (int)(idx & (LSEQ - 1));
  const int b = (int)(idx >> 13);
  floatx4 acc = *(const floatx4*)b_u2;
  for (int tap = 0; tap < 3; ++tap) {
    const int lg = l + tap - 1;
    if (lg < 0 || lg >= LSEQ) continue;
    const half8* hp = (const half8*)(hin + (((size_t)b * LSEQ + lg) << 8));
    const floatx4* wp = (const floatx4*)(w2T4 + tap * 1024);
    for (int q = 0; q < 32; ++q) {
      half8 hv = hp[q];
#pragma unroll
      for (int r = 0; r < 8; ++r) {
        floatx4 wv = wp[q * 8 + r];
        float h = (float)hv[r];
        acc[0] += h * wv[0]; acc[1] += h * wv[1]; acc[2] += h * wv[2]; acc[3] += h * wv[3];
      }
    }
  }
  floatx4 y;
#pragma unroll
  for (int r = 0; r < 4; ++r) y[r] = fmaxf(acc[r], 0.f);
  *(floatx4*)(out + ((size_t)b << 15) + (size_t)l * 4) = y;
}

// weight transforms (DENSE layout) + BN folding
__global__ void prep_kernel(
    const float* __restrict__ w_r1, const float* __restrict__ w_r2,
    const float* __restrict__ w_u1, const float* __restrict__ w_u2,
    const float* __restrict__ b_r1, const float* __restrict__ g1,
    const float* __restrict__ be1, const float* __restrict__ m1, const float* __restrict__ v1,
    const float* __restrict__ b_r2, const float* __restrict__ g2,
    const float* __restrict__ be2, const float* __restrict__ m2, const float* __restrict__ v2,
    const float* __restrict__ b_u1,
    _Float16* __restrict__ wT1, _Float16* __restrict__ wT2, _Float16* __restrict__ wTu1,
    float* __restrict__ wu2T4,
    float* __restrict__ sc1, float* __restrict__ sh1,
    float* __restrict__ sc2, float* __restrict__ sh2,
    float* __restrict__ scu1, float* __restrict__ shu1) {
  int idx = blockIdx.x * blockDim.x + threadIdx.x;
  if (idx < 3 * CCH * CCH) {
    // dense dst layout [tap][kc][co][32]: idx = ((tap*8+kc)*256+co)*32+c
    int tap = idx >> 16;               // / 65536
    int rem = idx & 65535;
    int kc = rem >> 13;                // / 8192
    int rem2 = rem & 8191;
    int co = rem2 >> 5, c = rem2 & 31;
    int ci = kc * 32 + c;
    size_t s = ((size_t)co * CCH + ci) * 3 + tap;
    wT1[idx] = (_Float16)w_r1[s];
    wT2[idx] = (_Float16)w_r2[s];
    wTu1[idx] = (_Float16)w_u1[s];
  }
  if (idx < 3 * CCH * 4) {  // wu2T4[tap][ci][co]
    int co = idx & 3;
    int ci = (idx >> 2) & 255;
    int tap = idx >> 10;
    wu2T4[idx] = w_u2[((size_t)co * CCH + ci) * 3 + tap];
  }
  if (idx < CCH) {
    float s1 = g1[idx] * rsqrtf(v1[idx] + 1e-5f);
    sc1[idx] = s1;
    sh1[idx] = (b_r1[idx] - m1[idx]) * s1 + be1[idx];
    float s2 = g2[idx] * rsqrtf(v2[idx] + 1e-5f);
    sc2[idx] = s2;
    sh2[idx] = (b_r2[idx] - m2[idx]) * s2 + be2[idx];
    scu1[idx] = 1.f;
    shu1[idx] = b_u1[idx];
  }
}

__global__ void diag_kernel(float* out, float v) { out[0] = v; }

extern "C" void kernel_launch(void* const* d_in, const int* in_sizes, int n_in,
                              void* d_out, int out_size, void* d_ws, size_t ws_size,
                              hipStream_t stream) {
  (void)in_sizes; (void)n_in; (void)out_size;
  const size_t HELEMS = (size_t)16 * LSEQ * CCH;      // 33,554,432
  const size_t HB = HELEMS * sizeof(_Float16);        // 67,108,864
  const size_t NEED = 2 * HB + 2u * 1024 * 1024;      // ~136 MiB
  if (ws_size < NEED) {
    diag_kernel<<<1, 1, 0, stream>>>((float*)d_out, 1000.0f + (float)(ws_size >> 20));
    return;
  }
  const float* x    = (const float*)d_in[0];
  const float* w_in = (const float*)d_in[3];
  const float* b_in = (const float*)d_in[4];
  const float* w_r1 = (const float*)d_in[5];
  const float* b_r1 = (const float*)d_in[6];
  const float* g1   = (const float*)d_in[7];
  const float* be1  = (const float*)d_in[8];
  const float* m1   = (const float*)d_in[9];
  const float* v1   = (const float*)d_in[10];
  const float* w_r2 = (const float*)d_in[11];
  const float* b_r2 = (const float*)d_in[12];
  const float* g2   = (const float*)d_in[13];
  const float* be2  = (const float*)d_in[14];
  const float* m2   = (const float*)d_in[15];
  const float* v2   = (const float*)d_in[16];
  const float* w_u1 = (const float*)d_in[17];
  const float* b_u1 = (const float*)d_in[18];
  const float* w_u2 = (const float*)d_in[19];
  const float* b_u2 = (const float*)d_in[20];

  char* ws = (char*)d_ws;
  _Float16* buf0 = (_Float16*)ws;
  _Float16* buf1 = (_Float16*)(ws + HB);
  _Float16* wT1  = (_Float16*)(ws + 2 * HB);
  _Float16* wT2  = wT1 + 3 * CCH * CCH;
  _Float16* wTu1 = wT2 + 3 * CCH * CCH;
  float* sc1  = (float*)(wTu1 + 3 * CCH * CCH);
  float* sh1  = sc1 + CCH;
  float* sc2  = sh1 + CCH;
  float* sh2  = sc2 + CCH;
  float* scu1 = sh2 + CCH;
  float* shu1 = scu1 + CCH;
  float* wu2T4 = shu1 + CCH;

  prep_kernel<<<768, 256, 0, stream>>>(w_r1, w_r2, w_u1, w_u2, b_r1, g1, be1, m1, v1,
                                       b_r2, g2, be2, m2, v2, b_u1,
                                       wT1, wT2, wTu1, wu2T4, sc1, sh1, sc2, sh2, scu1, shu1);
  conv_in_kernel<<<131072, 256, 0, stream>>>(x, w_in, b_in, buf0);
  const int grid = 16 * NT;  // 2048
  for (int k = 0; k < 32; ++k) {
    const _Float16* s = (k & 1) ? buf1 : buf0;
    _Float16* d = (k & 1) ? buf0 : buf1;
    res3<0><<<grid, 512, 0, stream>>>(s, d, wT1, wT2, sc1, sh1, sc2, sh2);
  }
  // state in buf0 after 32 resblocks
  res3<1><<<grid, 512, 0, stream>>>(buf0, buf1, wTu1, (const _Float16*)nullptr,
                                    scu1, shu1, (const float*)nullptr, (const float*)nullptr);
  conv_u2_kernel<<<512, 256, 0, stream>>>(buf1, wu2T4, b_u2, (float*)d_out);
}

// Round 12
// 4752.398 us; speedup vs baseline: 1.5484x; 1.5484x over previous
//
#include <hip/hip_runtime.h>

typedef _Float16 half8 __attribute__((ext_vector_type(8)));
typedef _Float16 half4 __attribute__((ext_vector_type(4)));
typedef float floatx4 __attribute__((ext_vector_type(4)));
typedef unsigned int uintx4 __attribute__((ext_vector_type(4)));

#define CCH 256
#define LSEQ 8192
#define LTILE 128                 // output rows per block (R10 geometry: best)
#define AROWS 132                 // staged h rows: l0-2 .. l0+129
#define NT 64                     // tiles per batch = 8192/128
#define ROWB 512
#define LDSB (AROWS * ROWB)       // 67584 -> 2 blocks/CU

__device__ __forceinline__ int swz(int row, int byte) {
  return row * ROWB + (byte ^ ((row & 7) << 4));
}
__device__ __forceinline__ floatx4 zero4() {
  floatx4 v; v[0] = 0.f; v[1] = 0.f; v[2] = 0.f; v[3] = 0.f; return v;
}

// R12 = R10 (best: 190us/dispatch) + two latency-hiding changes:
//  - register double-buffered WEIGHT PREFETCH: next (tap,kc)'s 4x1KB fragments
//    load while current MFMAs issue (hides ~200cy L2 latency; weights stream
//    from L2 every conv since 96KB/wave quarter >> 32KB L1)
//  - s_setprio(1) around MFMA clusters (T5): 2 blocks/CU at staggered phases
// MODE 0: dst = src + 0.15*bn2(conv2(relu(bn1(conv1(src)))))
// MODE 1: dst = relu(conv(src)*sc + sh)
template <int MODE>
__global__ __launch_bounds__(512, 1) void res4(
    const _Float16* __restrict__ src, _Float16* __restrict__ dst,
    const _Float16* __restrict__ wA, const _Float16* __restrict__ wB,
    const float* __restrict__ sc1v, const float* __restrict__ sh1v,
    const float* __restrict__ sc2v, const float* __restrict__ sh2v) {
  __shared__ __align__(16) char smem[LDSB];
  const int t = threadIdx.x;
  const int bx = blockIdx.x;
  const int b = bx >> 6;
  const int tile = bx & (NT - 1);
  const int l0 = tile * LTILE;

  // ---- stage A: 132 rows (row <-> l = l0-2+row), f16, swizzled, zero-padded
  for (int c = t; c < AROWS * 32; c += 512) {
    const int row = c >> 5, col = c & 31;
    const int l = l0 + row - 2;
    uintx4 v = {0u, 0u, 0u, 0u};
    if (l >= 0 && l < LSEQ)
      v = *(const uintx4*)(src + (((size_t)b * LSEQ + l) << 8) + col * 8);
    *(uintx4*)(smem + swz(row, col * 16)) = v;
  }
  __syncthreads();

  const int w = t >> 6, ln = t & 63;
  const int cg = w >> 1, lgrp = w & 1;  // co-group 0..3, l-half 0..1
  const int lrow = ln & 15, kgrp = ln >> 4;
  // per-wave weight base offset (elements) within a dense [tap][kc][co][32] matrix
  const size_t wbase = (size_t)(cg * 64 + lrow) * 32 + kgrp * 8;

  if constexpr (MODE == 0) {
    // ---- conv1 -> r1 rows r (l = l0-1+r), r 0..129 used.
    const int jtb = lgrp * 5;
    const int njt = lgrp ? 4 : 5;
    floatx4 acc[4][5];
#pragma unroll
    for (int i = 0; i < 4; ++i)
#pragma unroll
      for (int j = 0; j < 5; ++j) acc[i][j] = zero4();
    {
      const _Float16* wp = wA + wbase;  // it=0
      half8 a0 = *(const half8*)(wp);
      half8 a1 = *(const half8*)(wp + 16 * 32);
      half8 a2 = *(const half8*)(wp + 32 * 32);
      half8 a3 = *(const half8*)(wp + 48 * 32);
      for (int it = 0; it < 24; ++it) {
        // prefetch next iteration's weights (it=23 reloads current; discarded)
        const int nit = (it < 23) ? it + 1 : it;
        const _Float16* np = wA + (size_t)nit * (CCH * 32) + wbase;
        half8 n0 = *(const half8*)(np);
        half8 n1 = *(const half8*)(np + 16 * 32);
        half8 n2 = *(const half8*)(np + 32 * 32);
        half8 n3 = *(const half8*)(np + 48 * 32);
        const int tap = it >> 3, kc = it & 7;
        const int byt = kc * 64 + kgrp * 16;
        __builtin_amdgcn_s_setprio(1);
#pragma unroll
        for (int jj = 0; jj < 5; ++jj) {
          if (jj < njt) {
            int arow = (jtb + jj) * 16 + lrow + tap;  // A row = r + tap
            if (arow > AROWS - 1) arow = AROWS - 1;   // masked outputs only
            half8 bf = *(const half8*)(smem + swz(arow, byt));
            acc[0][jj] = __builtin_amdgcn_mfma_f32_16x16x32_f16(a0, bf, acc[0][jj], 0, 0, 0);
            acc[1][jj] = __builtin_amdgcn_mfma_f32_16x16x32_f16(a1, bf, acc[1][jj], 0, 0, 0);
            acc[2][jj] = __builtin_amdgcn_mfma_f32_16x16x32_f16(a2, bf, acc[2][jj], 0, 0, 0);
            acc[3][jj] = __builtin_amdgcn_mfma_f32_16x16x32_f16(a3, bf, acc[3][jj], 0, 0, 0);
          }
        }
        __builtin_amdgcn_s_setprio(0);
        a0 = n0; a1 = n1; a2 = n2; a3 = n3;
      }
    }
    __syncthreads();  // all conv1 A-reads done before r1 overwrites the buffer
    // epilogue 1: bn1+relu -> r1 into SAME buffer at row r; zero outside seq
#pragma unroll
    for (int i = 0; i < 4; ++i) {
      const int co = cg * 64 + i * 16 + kgrp * 4;
      floatx4 s = *(const floatx4*)(sc1v + co);
      floatx4 sh = *(const floatx4*)(sh1v + co);
#pragma unroll
      for (int jj = 0; jj < 5; ++jj) {
        if (jj < njt) {
          const int r = (jtb + jj) * 16 + lrow;
          if (r < 130) {
            const int l = l0 - 1 + r;
            const bool valid = (l >= 0) && (l < LSEQ);
            unsigned long long pk = 0;
#pragma unroll
            for (int q = 0; q < 4; ++q) {
              float y = acc[i][jj][q] * s[q] + sh[q];
              y = valid ? fmaxf(y, 0.f) : 0.f;
              unsigned short u = __builtin_bit_cast(unsigned short, (_Float16)y);
              pk |= (unsigned long long)u << (16 * q);
            }
            *(unsigned long long*)(smem + swz(r, co * 2)) = pk;
          }
        }
      }
    }
    __syncthreads();
    // ---- conv2: out row v (l = l0+v), reads r1 rows v..v+2; 4 j-tiles per lgrp
    floatx4 acc2[4][4];
#pragma unroll
    for (int i = 0; i < 4; ++i)
#pragma unroll
      for (int j = 0; j < 4; ++j) acc2[i][j] = zero4();
    {
      const _Float16* wp = wB + wbase;
      half8 a0 = *(const half8*)(wp);
      half8 a1 = *(const half8*)(wp + 16 * 32);
      half8 a2 = *(const half8*)(wp + 32 * 32);
      half8 a3 = *(const half8*)(wp + 48 * 32);
      for (int it = 0; it < 24; ++it) {
        const int nit = (it < 23) ? it + 1 : it;
        const _Float16* np = wB + (size_t)nit * (CCH * 32) + wbase;
        half8 n0 = *(const half8*)(np);
        half8 n1 = *(const half8*)(np + 16 * 32);
        half8 n2 = *(const half8*)(np + 32 * 32);
        half8 n3 = *(const half8*)(np + 48 * 32);
        const int tap = it >> 3, kc = it & 7;
        const int byt = kc * 64 + kgrp * 16;
        __builtin_amdgcn_s_setprio(1);
#pragma unroll
        for (int j = 0; j < 4; ++j) {
          const int brow = (lgrp * 4 + j) * 16 + lrow + tap;  // 0..129
          half8 bf = *(const half8*)(smem + swz(brow, byt));
          acc2[0][j] = __builtin_amdgcn_mfma_f32_16x16x32_f16(a0, bf, acc2[0][j], 0, 0, 0);
          acc2[1][j] = __builtin_amdgcn_mfma_f32_16x16x32_f16(a1, bf, acc2[1][j], 0, 0, 0);
          acc2[2][j] = __builtin_amdgcn_mfma_f32_16x16x32_f16(a2, bf, acc2[2][j], 0, 0, 0);
          acc2[3][j] = __builtin_amdgcn_mfma_f32_16x16x32_f16(a3, bf, acc2[3][j], 0, 0, 0);
        }
        __builtin_amdgcn_s_setprio(0);
        a0 = n0; a1 = n1; a2 = n2; a3 = n3;
      }
    }
    // epilogue 2: y = h + 0.15*bn2; h re-read from global src (L2/LLC-resident)
#pragma unroll
    for (int i = 0; i < 4; ++i) {
      const int co = cg * 64 + i * 16 + kgrp * 4;
      floatx4 s = *(const floatx4*)(sc2v + co);
      floatx4 sh = *(const floatx4*)(sh2v + co);
#pragma unroll
      for (int j = 0; j < 4; ++j) {
        const int v = (lgrp * 4 + j) * 16 + lrow;
        const int l = l0 + v;
        const size_t off = (((size_t)b * LSEQ + l) << 8) + co;
        half4 h = *(const half4*)(src + off);
        half4 o;
#pragma unroll
        for (int q = 0; q < 4; ++q)
          o[q] = (_Float16)((float)h[q] + 0.15f * (acc2[i][j][q] * s[q] + sh[q]));
        *(half4*)(dst + off) = o;
      }
    }
  } else {
    // MODE 1: out = relu(conv(A)*sc + sh); out row v reads A rows v+1..v+3
    floatx4 acc[4][4];
#pragma unroll
    for (int i = 0; i < 4; ++i)
#pragma unroll
      for (int j = 0; j < 4; ++j) acc[i][j] = zero4();
    for (int it = 0; it < 24; ++it) {
      const int tap = it >> 3, kc = it & 7;
      const _Float16* wp = wA + (size_t)it * (CCH * 32) + wbase;
      half8 a0 = *(const half8*)(wp);
      half8 a1 = *(const half8*)(wp + 16 * 32);
      half8 a2 = *(const half8*)(wp + 32 * 32);
      half8 a3 = *(const half8*)(wp + 48 * 32);
      const int byt = kc * 64 + kgrp * 16;
#pragma unroll
      for (int j = 0; j < 4; ++j) {
        const int arow = (lgrp * 4 + j) * 16 + lrow + 1 + tap;  // 1..130
        half8 bf = *(const half8*)(smem + swz(arow, byt));
        acc[0][j] = __builtin_amdgcn_mfma_f32_16x16x32_f16(a0, bf, acc[0][j], 0, 0, 0);
        acc[1][j] = __builtin_amdgcn_mfma_f32_16x16x32_f16(a1, bf, acc[1][j], 0, 0, 0);
        acc[2][j] = __builtin_amdgcn_mfma_f32_16x16x32_f16(a2, bf, acc[2][j], 0, 0, 0);
        acc[3][j] = __builtin_amdgcn_mfma_f32_16x16x32_f16(a3, bf, acc[3][j], 0, 0, 0);
      }
    }
#pragma unroll
    for (int i = 0; i < 4; ++i) {
      const int co = cg * 64 + i * 16 + kgrp * 4;
      floatx4 s = *(const floatx4*)(sc1v + co);
      floatx4 sh = *(const floatx4*)(sh1v + co);
#pragma unroll
      for (int j = 0; j < 4; ++j) {
        const int v = (lgrp * 4 + j) * 16 + lrow;
        const int l = l0 + v;
        half4 o;
#pragma unroll
        for (int q = 0; q < 4; ++q)
          o[q] = (_Float16)fmaxf(acc[i][j][q] * s[q] + sh[q], 0.f);
        *(half4*)(dst + (((size_t)b * LSEQ + l) << 8) + co) = o;
      }
    }
  }
}

// x[16][1][8192] -> h0[b][l][co] (f16) = relu(conv1d_{1->256}(x) + b_in)
__global__ void conv_in_kernel(const float* __restrict__ x, const float* __restrict__ w_in,
                               const float* __restrict__ b_in, _Float16* __restrict__ hout) {
  size_t idx = (size_t)blockIdx.x * blockDim.x + threadIdx.x;
  int co = (int)(idx & 255);
  size_t pos = idx >> 8;
  int l = (int)(pos & (LSEQ - 1));
  int b = (int)(pos >> 13);
  float acc = b_in[co];
#pragma unroll
  for (int k = 0; k < 3; ++k) {
    int lg = l + k - 1;
    if (lg >= 0 && lg < LSEQ) acc += w_in[co * 3 + k] * x[(size_t)b * LSEQ + lg];
  }
  hout[idx] = (_Float16)fmaxf(acc, 0.f);
}

// final conv 256->4 + bias + relu + pixel-shuffle: out[b][l*4+co]
__global__ __launch_bounds__(256) void conv_u2_kernel(
    const _Float16* __restrict__ hin, const float* __restrict__ w2T4 /*[tap][ci][4]*/,
    const float* __restrict__ b_u2, float* __restrict__ out) {
  const size_t idx = (size_t)blockIdx.x * 256 + threadIdx.x;  // = b*8192 + l
  const int l = (int)(idx & (LSEQ - 1));
  const int b = (int)(idx >> 13);
  floatx4 acc = *(const floatx4*)b_u2;
  for (int tap = 0; tap < 3; ++tap) {
    const int lg = l + tap - 1;
    if (lg < 0 || lg >= LSEQ) continue;
    const half8* hp = (const half8*)(hin + (((size_t)b * LSEQ + lg) << 8));
    const floatx4* wp = (const floatx4*)(w2T4 + tap * 1024);
    for (int q = 0; q < 32; ++q) {
      half8 hv = hp[q];
#pragma unroll
      for (int r = 0; r < 8; ++r) {
        floatx4 wv = wp[q * 8 + r];
        float h = (float)hv[r];
        acc[0] += h * wv[0]; acc[1] += h * wv[1]; acc[2] += h * wv[2]; acc[3] += h * wv[3];
      }
    }
  }
  floatx4 y;
#pragma unroll
  for (int r = 0; r < 4; ++r) y[r] = fmaxf(acc[r], 0.f);
  *(floatx4*)(out + ((size_t)b << 15) + (size_t)l * 4) = y;
}

// weight transforms (DENSE layout) + BN folding
__global__ void prep_kernel(
    const float* __restrict__ w_r1, const float* __restrict__ w_r2,
    const float* __restrict__ w_u1, const float* __restrict__ w_u2,
    const float* __restrict__ b_r1, const float* __restrict__ g1,
    const float* __restrict__ be1, const float* __restrict__ m1, const float* __restrict__ v1,
    const float* __restrict__ b_r2, const float* __restrict__ g2,
    const float* __restrict__ be2, const float* __restrict__ m2, const float* __restrict__ v2,
    const float* __restrict__ b_u1,
    _Float16* __restrict__ wT1, _Float16* __restrict__ wT2, _Float16* __restrict__ wTu1,
    float* __restrict__ wu2T4,
    float* __restrict__ sc1, float* __restrict__ sh1,
    float* __restrict__ sc2, float* __restrict__ sh2,
    float* __restrict__ scu1, float* __restrict__ shu1) {
  int idx = blockIdx.x * blockDim.x + threadIdx.x;
  if (idx < 3 * CCH * CCH) {
    // dense dst layout [tap][kc][co][32]: idx = ((tap*8+kc)*256+co)*32+c
    int tap = idx >> 16;
    int rem = idx & 65535;
    int kc = rem >> 13;
    int rem2 = rem & 8191;
    int co = rem2 >> 5, c = rem2 & 31;
    int ci = kc * 32 + c;
    size_t s = ((size_t)co * CCH + ci) * 3 + tap;
    wT1[idx] = (_Float16)w_r1[s];
    wT2[idx] = (_Float16)w_r2[s];
    wTu1[idx] = (_Float16)w_u1[s];
  }
  if (idx < 3 * CCH * 4) {  // wu2T4[tap][ci][co]
    int co = idx & 3;
    int ci = (idx >> 2) & 255;
    int tap = idx >> 10;
    wu2T4[idx] = w_u2[((size_t)co * CCH + ci) * 3 + tap];
  }
  if (idx < CCH) {
    float s1 = g1[idx] * rsqrtf(v1[idx] + 1e-5f);
    sc1[idx] = s1;
    sh1[idx] = (b_r1[idx] - m1[idx]) * s1 + be1[idx];
    float s2 = g2[idx] * rsqrtf(v2[idx] + 1e-5f);
    sc2[idx] = s2;
    sh2[idx] = (b_r2[idx] - m2[idx]) * s2 + be2[idx];
    scu1[idx] = 1.f;
    shu1[idx] = b_u1[idx];
  }
}

__global__ void diag_kernel(float* out, float v) { out[0] = v; }

extern "C" void kernel_launch(void* const* d_in, const int* in_sizes, int n_in,
                              void* d_out, int out_size, void* d_ws, size_t ws_size,
                              hipStream_t stream) {
  (void)in_sizes; (void)n_in; (void)out_size;
  const size_t HELEMS = (size_t)16 * LSEQ * CCH;      // 33,554,432
  const size_t HB = HELEMS * sizeof(_Float16);        // 67,108,864
  const size_t NEED = 2 * HB + 2u * 1024 * 1024;      // ~136 MiB
  if (ws_size < NEED) {
    diag_kernel<<<1, 1, 0, stream>>>((float*)d_out, 1000.0f + (float)(ws_size >> 20));
    return;
  }
  const float* x    = (const float*)d_in[0];
  const float* w_in = (const float*)d_in[3];
  const float* b_in = (const float*)d_in[4];
  const float* w_r1 = (const float*)d_in[5];
  const float* b_r1 = (const float*)d_in[6];
  const float* g1   = (const float*)d_in[7];
  const float* be1  = (const float*)d_in[8];
  const float* m1   = (const float*)d_in[9];
  const float* v1   = (const float*)d_in[10];
  const float* w_r2 = (const float*)d_in[11];
  const float* b_r2 = (const float*)d_in[12];
  const float* g2   = (const float*)d_in[13];
  const float* be2  = (const float*)d_in[14];
  const float* m2   = (const float*)d_in[15];
  const float* v2   = (const float*)d_in[16];
  const float* w_u1 = (const float*)d_in[17];
  const float* b_u1 = (const float*)d_in[18];
  const float* w_u2 = (const float*)d_in[19];
  const float* b_u2 = (const float*)d_in[20];

  char* ws = (char*)d_ws;
  _Float16* buf0 = (_Float16*)ws;
  _Float16* buf1 = (_Float16*)(ws + HB);
  _Float16* wT1  = (_Float16*)(ws + 2 * HB);
  _Float16* wT2  = wT1 + 3 * CCH * CCH;
  _Float16* wTu1 = wT2 + 3 * CCH * CCH;
  float* sc1  = (float*)(wTu1 + 3 * CCH * CCH);
  float* sh1  = sc1 + CCH;
  float* sc2  = sh1 + CCH;
  float* sh2  = sc2 + CCH;
  float* scu1 = sh2 + CCH;
  float* shu1 = scu1 + CCH;
  float* wu2T4 = shu1 + CCH;

  prep_kernel<<<768, 256, 0, stream>>>(w_r1, w_r2, w_u1, w_u2, b_r1, g1, be1, m1, v1,
                                       b_r2, g2, be2, m2, v2, b_u1,
                                       wT1, wT2, wTu1, wu2T4, sc1, sh1, sc2, sh2, scu1, shu1);
  conv_in_kernel<<<131072, 256, 0, stream>>>(x, w_in, b_in, buf0);
  const int grid = 16 * NT;  // 1024
  for (int k = 0; k < 32; ++k) {
    const _Float16* s = (k & 1) ? buf1 : buf0;
    _Float16* d = (k & 1) ? buf0 : buf1;
    res4<0><<<grid, 512, 0, stream>>>(s, d, wT1, wT2, sc1, sh1, sc2, sh2);
  }
  // state in buf0 after 32 resblocks
  res4<1><<<grid, 512, 0, stream>>>(buf0, buf1, wTu1, (const _Float16*)nullptr,
                                    scu1, shu1, (const float*)nullptr, (const float*)nullptr);
  conv_u2_kernel<<<512, 256, 0, stream>>>(buf1, wu2T4, b_u2, (float*)d_out);
}